// Round 4
// baseline (576.511 us; speedup 1.0000x reference)
//
#include <hip/hip_runtime.h>

// KnowledgeEmbedding loss as 8 fused fp32 GEMMs (M=4096, N=256, K=100) with
// softplus-sum epilogue and fused positive term.
// score(row,neg) = dot(head[h_row]+rvec, tail[neg]) + bias[t_row]
// loss = (1/B) * sum_rel [ sum_row softplus(-pos_row) + sum_{row,neg} softplus(score) ]
//
// Block = 64 rows x 128 negs, K chunked 5x20, double-buffered LDS, 1 barrier
// per chunk. Thread tile 8 rows x 4 negs. NOTE: hot loop is macro-expanded,
// no lambdas / indexed local arrays — R3's lambda version spilled 3.6 KB per
// thread to scratch (WRITE_SIZE 919 MB, 465 us).

#define EMBED   100
#define BATCH   4096
#define NUM_NEG 256
#define KC      20
#define BM      64
#define BN      128
#define NCHUNK  5

struct RelP {
    const float* head;
    const float* tail;
    const float* bias;
    int hc, tc;
};

struct Params {
    RelP rel[8];
    const float* rel_vecs;
    const int*   batch_idxs;
    const int*   neg_idxs;
    float*       out;
};

__device__ __forceinline__ float softplus_f(float x) {
    float e = __expf(-fabsf(x));
    return fmaxf(x, 0.0f) + __logf(1.0f + e);
}

__device__ __forceinline__ float4 fma4(float a, float4 b, float4 c) {
    c.x = fmaf(a, b.x, c.x);
    c.y = fmaf(a, b.y, c.y);
    c.z = fmaf(a, b.z, c.z);
    c.w = fmaf(a, b.w, c.w);
    return c;
}

#define LOAD_CHUNK(k0_)                                                  \
    do {                                                                 \
        pa0 = *(const float4*)(aptr0 + (k0_));                           \
        if (doA1) pa1 = *(const float4*)(aptr1 + (k0_));                 \
        pb0 = *(const float4*)(bptr0 + (k0_));                           \
        pb1 = *(const float4*)(bptr1 + (k0_));                           \
        if (doB2) pb2 = *(const float4*)(bptr2 + (k0_));                 \
    } while (0)

#define STORE_CHUNK(b_, k0_)                                             \
    do {                                                                 \
        const float4 rv0 = *(const float4*)(rvp0 + (k0_));               \
        As[b_][(aj0 * 4 + 0) * BM + arow0] = pa0.x + rv0.x;              \
        As[b_][(aj0 * 4 + 1) * BM + arow0] = pa0.y + rv0.y;              \
        As[b_][(aj0 * 4 + 2) * BM + arow0] = pa0.z + rv0.z;              \
        As[b_][(aj0 * 4 + 3) * BM + arow0] = pa0.w + rv0.w;              \
        if (doA1) {                                                      \
            const float4 rv1 = *(const float4*)(rvp1 + (k0_));           \
            As[b_][16 * BM + tid] = pa1.x + rv1.x;                       \
            As[b_][17 * BM + tid] = pa1.y + rv1.y;                       \
            As[b_][18 * BM + tid] = pa1.z + rv1.z;                       \
            As[b_][19 * BM + tid] = pa1.w + rv1.w;                       \
        }                                                                \
        Bs[b_][(bj0 * 4 + 0) * BN + bneg0] = pb0.x;                      \
        Bs[b_][(bj0 * 4 + 1) * BN + bneg0] = pb0.y;                      \
        Bs[b_][(bj0 * 4 + 2) * BN + bneg0] = pb0.z;                      \
        Bs[b_][(bj0 * 4 + 3) * BN + bneg0] = pb0.w;                      \
        Bs[b_][(bj0 * 4 + 8) * BN + bneg0] = pb1.x;                      \
        Bs[b_][(bj0 * 4 + 9) * BN + bneg0] = pb1.y;                      \
        Bs[b_][(bj0 * 4 + 10) * BN + bneg0] = pb1.z;                     \
        Bs[b_][(bj0 * 4 + 11) * BN + bneg0] = pb1.w;                     \
        if (doB2) {                                                      \
            Bs[b_][16 * BN + tid] = pb2.x;                               \
            Bs[b_][17 * BN + tid] = pb2.y;                               \
            Bs[b_][18 * BN + tid] = pb2.z;                               \
            Bs[b_][19 * BN + tid] = pb2.w;                               \
        }                                                                \
    } while (0)

#define COMPUTE_CHUNK(b_)                                                \
    do {                                                                 \
        _Pragma("unroll")                                                \
        for (int k = 0; k < KC; ++k) {                                   \
            const float4 a0 = *(const float4*)&As[b_][k * BM + tx * 8];  \
            const float4 a1 = *(const float4*)&As[b_][k * BM + tx * 8 + 4]; \
            const float4 bv = *(const float4*)&Bs[b_][k * BN + ty * 4];  \
            c0 = fma4(a0.x, bv, c0);                                     \
            c1 = fma4(a0.y, bv, c1);                                     \
            c2 = fma4(a0.z, bv, c2);                                     \
            c3 = fma4(a0.w, bv, c3);                                     \
            c4 = fma4(a1.x, bv, c4);                                     \
            c5 = fma4(a1.y, bv, c5);                                     \
            c6 = fma4(a1.z, bv, c6);                                     \
            c7 = fma4(a1.w, bv, c7);                                     \
        }                                                                \
    } while (0)

__launch_bounds__(256, 4)
__global__ void ke_kernel(Params p) {
    const int bid = blockIdx.x;
    const int r   = bid & 7;
    const int rb  = (bid >> 3) & 63;
    const int nb  = bid >> 9;            // 0..1
    const int tid = threadIdx.x;
    const int tx  = tid & 7;             // rows tx*8 .. +7
    const int ty  = tid >> 3;            // negs ty*4 .. +3

    __shared__ float As[2][KC * BM];     // [k][row], ex = head+rvec fused
    __shared__ float Bs[2][KC * BN];     // [k][neg]

    const RelP rp = p.rel[r];

    // ---- staging assignments (fixed across chunks) ----
    const int arow0 = tid & 63;
    const int aj0   = tid >> 6;                       // 0..3 (wave index)
    const int h0    = p.batch_idxs[(rb * BM + arow0) * 8 + rp.hc];
    const float* aptr0 = rp.head + (size_t)h0 * EMBED + aj0 * 4;
    const float* rvp0  = p.rel_vecs + r * EMBED + aj0 * 4;
    const bool  doA1 = (tid < 64);
    const int   h1   = doA1 ? p.batch_idxs[(rb * BM + tid) * 8 + rp.hc] : 0;
    const float* aptr1 = rp.head + (size_t)h1 * EMBED + 16;
    const float* rvp1  = p.rel_vecs + r * EMBED + 16;

    const int bneg0 = tid & 127;
    const int bj0   = tid >> 7;                       // 0..1
    const int n0    = p.neg_idxs[r * NUM_NEG + nb * BN + bneg0];
    const float* bptr0 = rp.tail + (size_t)n0 * EMBED + bj0 * 4;
    const float* bptr1 = bptr0 + 8;                   // (bj0+2)*4
    const bool  doB2 = (tid < 128);
    const int   n2   = doB2 ? p.neg_idxs[r * NUM_NEG + nb * BN + tid] : 0;
    const float* bptr2 = rp.tail + (size_t)n2 * EMBED + 16;

    float4 c0 = {0,0,0,0}, c1 = {0,0,0,0}, c2 = {0,0,0,0}, c3 = {0,0,0,0};
    float4 c4 = {0,0,0,0}, c5 = {0,0,0,0}, c6 = {0,0,0,0}, c7 = {0,0,0,0};
    float4 pa0, pa1, pb0, pb1, pb2;

    // ---- pipelined main loop: 1 barrier per chunk ----
    LOAD_CHUNK(0);
    STORE_CHUNK(0, 0);
    __syncthreads();
#pragma unroll
    for (int kc = 0; kc < NCHUNK; ++kc) {
        if (kc + 1 < NCHUNK) LOAD_CHUNK((kc + 1) * KC);
        if (kc & 1) COMPUTE_CHUNK(1); else COMPUTE_CHUNK(0);
        if (kc + 1 < NCHUNK) {
            // buffer (kc+1)&1 was last computed in iter kc-1; barrier at end
            // of kc-1 guarantees all waves are done with it -> safe to store.
            if ((kc + 1) & 1) STORE_CHUNK(1, (kc + 1) * KC);
            else              STORE_CHUNK(0, (kc + 1) * KC);
            __syncthreads();
        }
    }

    // ---- epilogue: bias + softplus + sum ----
    float local = 0.0f;
#pragma unroll
    for (int i = 0; i < 8; ++i) {
        const int grow = rb * BM + tx * 8 + i;
        const int t    = p.batch_idxs[grow * 8 + rp.tc];
        const float bias = rp.bias[t];
        float4 ci;
        switch (i) {
            case 0: ci = c0; break; case 1: ci = c1; break;
            case 2: ci = c2; break; case 3: ci = c3; break;
            case 4: ci = c4; break; case 5: ci = c5; break;
            case 6: ci = c6; break; default: ci = c7; break;
        }
        local += softplus_f(ci.x + bias);
        local += softplus_f(ci.y + bias);
        local += softplus_f(ci.z + bias);
        local += softplus_f(ci.w + bias);
    }

    // ---- fused positive term: nb==0 blocks, one row per thread 0..63 ----
    if (nb == 0 && tid < BM) {
        const int row = rb * BM + tid;
        const int h = p.batch_idxs[row * 8 + rp.hc];
        const int t = p.batch_idxs[row * 8 + rp.tc];
        const float4* __restrict__ hv  = (const float4*)(rp.head + (size_t)h * EMBED);
        const float4* __restrict__ rv4 = (const float4*)(p.rel_vecs + r * EMBED);
        const float4* __restrict__ tv  = (const float4*)(rp.tail + (size_t)t * EMBED);
        float d0 = 0.f, d1 = 0.f, d2 = 0.f, d3 = 0.f;
#pragma unroll
        for (int j = 0; j < EMBED / 4; ++j) {
            const float4 a = hv[j];
            const float4 b = rv4[j];
            const float4 v = tv[j];
            d0 = fmaf(a.x + b.x, v.x, d0);
            d1 = fmaf(a.y + b.y, v.y, d1);
            d2 = fmaf(a.z + b.z, v.z, d2);
            d3 = fmaf(a.w + b.w, v.w, d3);
        }
        const float pos = ((d0 + d1) + (d2 + d3)) + rp.bias[t];
        local += softplus_f(-pos);
    }

    // ---- block reduction + one atomic ----
#pragma unroll
    for (int off = 32; off > 0; off >>= 1)
        local += __shfl_down(local, off, 64);
    __shared__ float wsum[4];
    const int wid  = tid >> 6;
    const int lane = tid & 63;
    if (lane == 0) wsum[wid] = local;
    __syncthreads();
    if (tid == 0) {
        const float s = (wsum[0] + wsum[1]) + (wsum[2] + wsum[3]);
        atomicAdd(p.out, s * (1.0f / BATCH));
    }
}

extern "C" void kernel_launch(void* const* d_in, const int* in_sizes, int n_in,
                              void* d_out, int out_size, void* d_ws, size_t ws_size,
                              hipStream_t stream) {
    const float* user  = (const float*)d_in[0];
    const float* prod  = (const float*)d_in[1];
    const float* word  = (const float*)d_in[2];
    const float* brand = (const float*)d_in[3];
    const float* cat   = (const float*)d_in[4];
    const float* rprod = (const float*)d_in[5];

    Params p;
    p.rel_vecs   = (const float*)d_in[6];
    p.batch_idxs = (const int*)d_in[15];
    p.neg_idxs   = (const int*)d_in[16];
    p.out        = (float*)d_out;

    p.rel[0] = {user, prod,  (const float*)d_in[7],  0, 1};  // purchase
    p.rel[1] = {user, word,  (const float*)d_in[8],  0, 2};  // mentions
    p.rel[2] = {prod, word,  (const float*)d_in[9],  1, 2};  // describe
    p.rel[3] = {prod, brand, (const float*)d_in[10], 1, 3};  // produced
    p.rel[4] = {prod, cat,   (const float*)d_in[11], 1, 4};  // belongs
    p.rel[5] = {prod, rprod, (const float*)d_in[12], 1, 5};  // also_bought
    p.rel[6] = {prod, rprod, (const float*)d_in[13], 1, 6};  // also_viewed
    p.rel[7] = {prod, rprod, (const float*)d_in[14], 1, 7};  // together

    hipMemsetAsync(d_out, 0, sizeof(float), stream);
    ke_kernel<<<1024, 256, 0, stream>>>(p);
}

// Round 5
// 168.721 us; speedup vs baseline: 3.4170x; 3.4170x over previous
//
#include <hip/hip_runtime.h>

// KnowledgeEmbedding loss as 8 fused fp32 GEMMs (M=4096, N=256, K=100) with
// softplus-sum epilogue and fused positive term.
// score(row,neg) = dot(head[h_row]+rvec, tail[neg]) + bias[t_row]
// loss = (1/B) * sum_rel [ sum_row softplus(-pos_row) + sum_{row,neg} softplus(score) ]
//
// Block = 64 rows x 128 negs, K chunked 5x20, SINGLE-buffered LDS (2 barriers
// per chunk). Thread tile 4 rows x 8 negs (tx=tid&15, ty=tid>>4).
// HISTORY: double-buffer + cross-barrier prefetch regs + launch_bounds(256,4)
// made the allocator settle at 64 VGPR and spill 3.5 KB/thread to scratch
// (WRITE_SIZE 921 MB, 465 us; R3+R4 identical). launch_bounds(256,2) +
// single buffer is the empirically non-spilling shape (R1/R2).

#define EMBED   100
#define BATCH   4096
#define NUM_NEG 256
#define KC      20
#define BM      64
#define BN      128
#define NCHUNK  5

struct RelP {
    const float* head;
    const float* tail;
    const float* bias;
    int hc, tc;
};

struct Params {
    RelP rel[8];
    const float* rel_vecs;
    const int*   batch_idxs;
    const int*   neg_idxs;
    float*       out;
};

__device__ __forceinline__ float softplus_f(float x) {
    float e = __expf(-fabsf(x));
    return fmaxf(x, 0.0f) + __logf(1.0f + e);
}

__device__ __forceinline__ float4 fma4(float a, float4 b, float4 c) {
    c.x = fmaf(a, b.x, c.x);
    c.y = fmaf(a, b.y, c.y);
    c.z = fmaf(a, b.z, c.z);
    c.w = fmaf(a, b.w, c.w);
    return c;
}

__launch_bounds__(256, 2)
__global__ void ke_kernel(Params p) {
    // grid: 8 rel * 64 rowblocks * 2 negblocks = 1024 blocks
    const int bid = blockIdx.x;
    const int r   = bid & 7;
    const int rb  = (bid >> 3) & 63;
    const int nb  = bid >> 9;            // 0..1
    const int tid = threadIdx.x;
    const int tx  = tid & 15;            // rows tx*4 .. +3
    const int ty  = tid >> 4;            // negs ty*8 .. +7

    __shared__ float As[KC * BM];        // [k][row], ex = head+rvec fused
    __shared__ float Bs[KC * BN];        // [k][neg]

    const RelP rp = p.rel[r];

    // ---- staging assignments (fixed across k-chunks) ----
    // A: 320 float4/chunk. f=tid: row=tid&63, j=tid>>6; f=256+tid (tid<64): row=tid, j=4
    const int arow0 = tid & 63;
    const int aj0   = tid >> 6;
    const int h0    = p.batch_idxs[(rb * BM + arow0) * 8 + rp.hc];
    const float* aptr0 = rp.head + (size_t)h0 * EMBED + aj0 * 4;
    const float* rvp0  = p.rel_vecs + r * EMBED + aj0 * 4;
    const bool  doA1 = (tid < 64);
    const int   h1   = doA1 ? p.batch_idxs[(rb * BM + tid) * 8 + rp.hc] : 0;
    const float* aptr1 = rp.head + (size_t)h1 * EMBED + 16;
    const float* rvp1  = p.rel_vecs + r * EMBED + 16;

    // B: 640 float4/chunk. f=tid: neg=tid&127, j=tid>>7; f=tid+256: j+2;
    //    f=tid+512 (tid<128): neg=tid, j=4
    const int bneg0 = tid & 127;
    const int bj0   = tid >> 7;
    const int n0    = p.neg_idxs[r * NUM_NEG + nb * BN + bneg0];
    const float* bptr0 = rp.tail + (size_t)n0 * EMBED + bj0 * 4;
    const float* bptr1 = bptr0 + 8;
    const bool  doB2 = (tid < 128);
    const int   n2   = doB2 ? p.neg_idxs[r * NUM_NEG + nb * BN + tid] : 0;
    const float* bptr2 = rp.tail + (size_t)n2 * EMBED + 16;

    // 4 rows x 8 negs accumulator: c<i>0 = negs 0-3, c<i>1 = negs 4-7 of row i
    float4 c00 = {0,0,0,0}, c01 = {0,0,0,0};
    float4 c10 = {0,0,0,0}, c11 = {0,0,0,0};
    float4 c20 = {0,0,0,0}, c21 = {0,0,0,0};
    float4 c30 = {0,0,0,0}, c31 = {0,0,0,0};

#pragma unroll
    for (int kc = 0; kc < NCHUNK; ++kc) {
        const int k0 = kc * KC;

        // ---- stage A (ex = head + rvec), [k][row] ----
        {
            const float4 a  = *(const float4*)(aptr0 + k0);
            const float4 rv = *(const float4*)(rvp0 + k0);
            const int kb = aj0 * 4;
            As[(kb + 0) * BM + arow0] = a.x + rv.x;
            As[(kb + 1) * BM + arow0] = a.y + rv.y;
            As[(kb + 2) * BM + arow0] = a.z + rv.z;
            As[(kb + 3) * BM + arow0] = a.w + rv.w;
        }
        if (doA1) {
            const float4 a  = *(const float4*)(aptr1 + k0);
            const float4 rv = *(const float4*)(rvp1 + k0);
            As[16 * BM + tid] = a.x + rv.x;
            As[17 * BM + tid] = a.y + rv.y;
            As[18 * BM + tid] = a.z + rv.z;
            As[19 * BM + tid] = a.w + rv.w;
        }
        // ---- stage B, [k][neg] ----
        {
            const float4 b = *(const float4*)(bptr0 + k0);
            const int kb = bj0 * 4;
            Bs[(kb + 0) * BN + bneg0] = b.x;
            Bs[(kb + 1) * BN + bneg0] = b.y;
            Bs[(kb + 2) * BN + bneg0] = b.z;
            Bs[(kb + 3) * BN + bneg0] = b.w;
        }
        {
            const float4 b = *(const float4*)(bptr1 + k0);
            const int kb = bj0 * 4 + 8;
            Bs[(kb + 0) * BN + bneg0] = b.x;
            Bs[(kb + 1) * BN + bneg0] = b.y;
            Bs[(kb + 2) * BN + bneg0] = b.z;
            Bs[(kb + 3) * BN + bneg0] = b.w;
        }
        if (doB2) {
            const float4 b = *(const float4*)(bptr2 + k0);
            Bs[16 * BN + tid] = b.x;
            Bs[17 * BN + tid] = b.y;
            Bs[18 * BN + tid] = b.z;
            Bs[19 * BN + tid] = b.w;
        }
        __syncthreads();

        // ---- inner product over this k-chunk ----
#pragma unroll 4
        for (int k = 0; k < KC; ++k) {
            const float4 a  = *(const float4*)&As[k * BM + tx * 4];
            const float4 b0 = *(const float4*)&Bs[k * BN + ty * 8];
            const float4 b1 = *(const float4*)&Bs[k * BN + ty * 8 + 4];
            c00 = fma4(a.x, b0, c00); c01 = fma4(a.x, b1, c01);
            c10 = fma4(a.y, b0, c10); c11 = fma4(a.y, b1, c11);
            c20 = fma4(a.z, b0, c20); c21 = fma4(a.z, b1, c21);
            c30 = fma4(a.w, b0, c30); c31 = fma4(a.w, b1, c31);
        }
        __syncthreads();
    }

    // ---- epilogue: bias + softplus + sum ----
    float local = 0.0f;
    {
        const int g0 = rb * BM + tx * 4;
        const float bias0 = rp.bias[p.batch_idxs[(g0 + 0) * 8 + rp.tc]];
        const float bias1 = rp.bias[p.batch_idxs[(g0 + 1) * 8 + rp.tc]];
        const float bias2 = rp.bias[p.batch_idxs[(g0 + 2) * 8 + rp.tc]];
        const float bias3 = rp.bias[p.batch_idxs[(g0 + 3) * 8 + rp.tc]];
        local += softplus_f(c00.x + bias0) + softplus_f(c00.y + bias0)
               + softplus_f(c00.z + bias0) + softplus_f(c00.w + bias0)
               + softplus_f(c01.x + bias0) + softplus_f(c01.y + bias0)
               + softplus_f(c01.z + bias0) + softplus_f(c01.w + bias0);
        local += softplus_f(c10.x + bias1) + softplus_f(c10.y + bias1)
               + softplus_f(c10.z + bias1) + softplus_f(c10.w + bias1)
               + softplus_f(c11.x + bias1) + softplus_f(c11.y + bias1)
               + softplus_f(c11.z + bias1) + softplus_f(c11.w + bias1);
        local += softplus_f(c20.x + bias2) + softplus_f(c20.y + bias2)
               + softplus_f(c20.z + bias2) + softplus_f(c20.w + bias2)
               + softplus_f(c21.x + bias2) + softplus_f(c21.y + bias2)
               + softplus_f(c21.z + bias2) + softplus_f(c21.w + bias2);
        local += softplus_f(c30.x + bias3) + softplus_f(c30.y + bias3)
               + softplus_f(c30.z + bias3) + softplus_f(c30.w + bias3)
               + softplus_f(c31.x + bias3) + softplus_f(c31.y + bias3)
               + softplus_f(c31.z + bias3) + softplus_f(c31.w + bias3);
    }

    // ---- fused positive term: nb==0 blocks, one row per thread 0..63 ----
    if (nb == 0 && tid < BM) {
        const int row = rb * BM + tid;
        const int h = p.batch_idxs[row * 8 + rp.hc];
        const int t = p.batch_idxs[row * 8 + rp.tc];
        const float4* __restrict__ hv  = (const float4*)(rp.head + (size_t)h * EMBED);
        const float4* __restrict__ rv4 = (const float4*)(p.rel_vecs + r * EMBED);
        const float4* __restrict__ tv  = (const float4*)(rp.tail + (size_t)t * EMBED);
        float d0 = 0.f, d1 = 0.f, d2 = 0.f, d3 = 0.f;
#pragma unroll
        for (int j = 0; j < EMBED / 4; ++j) {
            const float4 a = hv[j];
            const float4 b = rv4[j];
            const float4 v = tv[j];
            d0 = fmaf(a.x + b.x, v.x, d0);
            d1 = fmaf(a.y + b.y, v.y, d1);
            d2 = fmaf(a.z + b.z, v.z, d2);
            d3 = fmaf(a.w + b.w, v.w, d3);
        }
        const float pos = ((d0 + d1) + (d2 + d3)) + rp.bias[t];
        local += softplus_f(-pos);
    }

    // ---- block reduction + one atomic ----
#pragma unroll
    for (int off = 32; off > 0; off >>= 1)
        local += __shfl_down(local, off, 64);
    __shared__ float wsum[4];
    const int wid  = tid >> 6;
    const int lane = tid & 63;
    if (lane == 0) wsum[wid] = local;
    __syncthreads();
    if (tid == 0) {
        const float s = (wsum[0] + wsum[1]) + (wsum[2] + wsum[3]);
        atomicAdd(p.out, s * (1.0f / BATCH));
    }
}

extern "C" void kernel_launch(void* const* d_in, const int* in_sizes, int n_in,
                              void* d_out, int out_size, void* d_ws, size_t ws_size,
                              hipStream_t stream) {
    const float* user  = (const float*)d_in[0];
    const float* prod  = (const float*)d_in[1];
    const float* word  = (const float*)d_in[2];
    const float* brand = (const float*)d_in[3];
    const float* cat   = (const float*)d_in[4];
    const float* rprod = (const float*)d_in[5];

    Params p;
    p.rel_vecs   = (const float*)d_in[6];
    p.batch_idxs = (const int*)d_in[15];
    p.neg_idxs   = (const int*)d_in[16];
    p.out        = (float*)d_out;

    p.rel[0] = {user, prod,  (const float*)d_in[7],  0, 1};  // purchase
    p.rel[1] = {user, word,  (const float*)d_in[8],  0, 2};  // mentions
    p.rel[2] = {prod, word,  (const float*)d_in[9],  1, 2};  // describe
    p.rel[3] = {prod, brand, (const float*)d_in[10], 1, 3};  // produced
    p.rel[4] = {prod, cat,   (const float*)d_in[11], 1, 4};  // belongs
    p.rel[5] = {prod, rprod, (const float*)d_in[12], 1, 5};  // also_bought
    p.rel[6] = {prod, rprod, (const float*)d_in[13], 1, 6};  // also_viewed
    p.rel[7] = {prod, rprod, (const float*)d_in[14], 1, 7};  // together

    hipMemsetAsync(d_out, 0, sizeof(float), stream);
    ke_kernel<<<1024, 256, 0, stream>>>(p);
}